// Round 15
// baseline (6333.500 us; speedup 1.0000x reference)
//
#include <hip/hip_runtime.h>
#include <hip/hip_bf16.h>

// LSTM T=512 B=32 IN=H=1024 L=2. fp32 in/out, bf16 MFMA internally.
// Round 15: parity-tagged h (freshness fused into data). h stored as f32 with
// a 3-bit step tag in mantissa LSBs, in 16-slot rings; consumers retry-load
// via agent atomics until tags match. No flags/EP on the critical cycle.
// l1 progress words only provide slack-12 ring backpressure for l0.

namespace {
constexpr int T_STEPS = 512;
constexpr int BATCH   = 32;
constexpr int HID     = 1024;
constexpr int G4H     = 4096;
constexpr int KCAT    = 2048;
constexpr int BH      = BATCH * HID;                 // 32768
constexpr size_t MEM_ELEMS = (size_t)T_STEPS * BH;   // 16,777,216

// ---- parity-version workspace layout (bytes) ----
constexpr size_t OFF_W    = 0;
constexpr size_t SZ_W     = (size_t)2 * G4H * KCAT * 2;     // 33.55 MB bf16 W_cat
constexpr size_t OFF_BIAS = OFF_W + SZ_W;                   // f32 [2][4096]
constexpr size_t OFF_H0R  = OFF_BIAS + 32768;               // f32 ring [16][32][1024]
constexpr size_t SZ_RING  = (size_t)16 * BH * 4;            // 2 MB
constexpr size_t OFF_H1R  = OFF_H0R + SZ_RING;
constexpr size_t OFF_FLAG = OFF_H1R + SZ_RING;              // l1 progress u32[128]@64B
constexpr size_t SZ_FLAG  = 8192;
constexpr size_t OFF_X    = OFF_FLAG + SZ_FLAG;             // bf16 X [512][32][1024]
constexpr size_t WS_PAR   = OFF_X + MEM_ELEMS * 2;          // ~69.7 MB
// ---- tier-2 layout ----
constexpr size_t T2_BIAS = OFF_W + SZ_W;
constexpr size_t T2_H0   = T2_BIAS + 32768;
constexpr size_t T2_H1   = T2_H0 + (size_t)2 * BH * 2;
constexpr size_t WS_STEP = T2_H1 + (size_t)2 * BH * 2;
}

typedef __attribute__((ext_vector_type(8))) short short8;
typedef __attribute__((ext_vector_type(4))) float f32x4;
typedef unsigned short u16;
typedef unsigned long long u64;

__device__ inline unsigned short f2bf(float x) {
  unsigned u = __builtin_bit_cast(unsigned, x);
  u += 0x7fffu + ((u >> 16) & 1u);          // RNE
  return (unsigned short)(u >> 16);
}
__device__ inline float sigm(float x) { return 1.0f / (1.0f + __expf(-x)); }
__device__ inline unsigned short bf_of_u32(unsigned w) {
  return f2bf(__builtin_bit_cast(float, w));
}

// ---------------- conversion: W_cat bf16, bias sum, ring slot0, X bf16 ----------------
__global__ void cvt_kernel(const float* __restrict__ Wih, const float* __restrict__ Whh,
                           const float* __restrict__ bih, const float* __restrict__ bhh,
                           const float* __restrict__ h0, const float* __restrict__ input,
                           u16* __restrict__ Wcat, float* __restrict__ bias,
                           unsigned* __restrict__ H0R, unsigned* __restrict__ H1R,
                           u16* __restrict__ Xbf) {
  size_t idx = (size_t)blockIdx.x * blockDim.x + threadIdx.x;
  size_t stride = (size_t)gridDim.x * blockDim.x;
  const size_t NW = (size_t)2 * G4H * KCAT;
  for (size_t i = idx; i < NW; i += stride) {
    size_t ln = i >> 11;                 // l*4096 + n
    int k = (int)(i & 2047);
    float v = (k < HID) ? Wih[ln * HID + k] : Whh[ln * HID + (k - HID)];
    Wcat[i] = f2bf(v);
  }
  for (size_t i = idx; i < (size_t)2 * G4H; i += stride) bias[i] = bih[i] + bhh[i];
  // ring slot 0 = h at t=0, tag (0%7)+1 = 1
  for (size_t i = idx; i < (size_t)BH; i += stride) {
    unsigned a = (__builtin_bit_cast(unsigned, h0[i]) & ~7u) | 1u;
    unsigned b = (__builtin_bit_cast(unsigned, h0[BH + i]) & ~7u) | 1u;
    H0R[i] = a;
    H1R[i] = b;
  }
  if (Xbf) {
    for (size_t i = idx; i < MEM_ELEMS; i += stride) Xbf[i] = f2bf(input[i]);
  }
}

// plain-bf16 x path (l0 wid 0,1): batched cached loads then MFMA (r8-proven)
__device__ __attribute__((always_inline)) void mfma_batched_pl(
    const unsigned char* smem, const u16* ab0, const u16* ab1,
    int kbyte_base, int xsw, int l15,
    f32x4& acc00, f32x4& acc01, f32x4& acc10, f32x4& acc11) {
  u64 ra0[16], ra1[16], rb0[16], rb1[16];
  #pragma unroll
  for (int ks = 0; ks < 16; ++ks) {
    const u64* q0 = (const u64*)(ab0 + ks * 32);
    const u64* q1 = (const u64*)(ab1 + ks * 32);
    ra0[ks] = q0[0]; ra1[ks] = q0[1];
    rb0[ks] = q1[0]; rb1[ks] = q1[1];
  }
  #pragma unroll
  for (int ks = 0; ks < 16; ++ks) {
    const int kb2 = kbyte_base + ks * 64;
    short8 b0 = *(const short8*)(smem + l15 * 4096 + (kb2 ^ xsw));
    short8 b1 = *(const short8*)(smem + (16 + l15) * 4096 + (kb2 ^ xsw));
    union { u64 u[2]; short8 s; } ua, ub;
    ua.u[0] = ra0[ks]; ua.u[1] = ra1[ks];
    ub.u[0] = rb0[ks]; ub.u[1] = rb1[ks];
    acc00 = __builtin_amdgcn_mfma_f32_16x16x32_bf16(ua.s, b0, acc00, 0, 0, 0);
    acc01 = __builtin_amdgcn_mfma_f32_16x16x32_bf16(ua.s, b1, acc01, 0, 0, 0);
    acc10 = __builtin_amdgcn_mfma_f32_16x16x32_bf16(ub.s, b0, acc10, 0, 0, 0);
    acc11 = __builtin_amdgcn_mfma_f32_16x16x32_bf16(ub.s, b1, acc11, 0, 0, 0);
  }
}

// parity-tagged f32 h path: retry-load 8 ks-iters (K=256) until all tags match,
// then convert to bf16 frags and MFMA. Two calls cover a wave's K=512 slice.
__device__ __attribute__((always_inline)) void mfma_parity_half(
    const unsigned char* smem, const unsigned* hb,
    int row0col, int row1col, unsigned tag, int ksbase,
    int kbyte_base, int xsw, int l15,
    f32x4& acc00, f32x4& acc01, f32x4& acc10, f32x4& acc11) {
  u64 v0[32], v1[32];
  for (;;) {
    #pragma unroll
    for (int ks = 0; ks < 8; ++ks) {
      const int c = (ksbase + ks) * 32;
      const u64* q0 = (const u64*)(hb + row0col + c);
      const u64* q1 = (const u64*)(hb + row1col + c);
      #pragma unroll
      for (int e = 0; e < 4; ++e) {
        v0[ks * 4 + e] = __hip_atomic_load(q0 + e, __ATOMIC_RELAXED, __HIP_MEMORY_SCOPE_AGENT);
        v1[ks * 4 + e] = __hip_atomic_load(q1 + e, __ATOMIC_RELAXED, __HIP_MEMORY_SCOPE_AGENT);
      }
    }
    bool ok = true;
    #pragma unroll
    for (int e = 0; e < 32; ++e) {
      ok &= (((unsigned)v0[e] & 7u) == tag) & (((unsigned)(v0[e] >> 32) & 7u) == tag);
      ok &= (((unsigned)v1[e] & 7u) == tag) & (((unsigned)(v1[e] >> 32) & 7u) == tag);
    }
    if (__all((int)ok)) break;
    __builtin_amdgcn_s_sleep(1);
  }
  #pragma unroll
  for (int ks = 0; ks < 8; ++ks) {
    short8 a0, a1;
    #pragma unroll
    for (int e = 0; e < 4; ++e) {
      a0[e * 2]     = (short)bf_of_u32((unsigned)v0[ks * 4 + e]);
      a0[e * 2 + 1] = (short)bf_of_u32((unsigned)(v0[ks * 4 + e] >> 32));
      a1[e * 2]     = (short)bf_of_u32((unsigned)v1[ks * 4 + e]);
      a1[e * 2 + 1] = (short)bf_of_u32((unsigned)(v1[ks * 4 + e] >> 32));
    }
    const int kb2 = kbyte_base + (ksbase + ks) * 64;
    short8 b0 = *(const short8*)(smem + l15 * 4096 + (kb2 ^ xsw));
    short8 b1 = *(const short8*)(smem + (16 + l15) * 4096 + (kb2 ^ xsw));
    acc00 = __builtin_amdgcn_mfma_f32_16x16x32_bf16(a0, b0, acc00, 0, 0, 0);
    acc01 = __builtin_amdgcn_mfma_f32_16x16x32_bf16(a0, b1, acc01, 0, 0, 0);
    acc10 = __builtin_amdgcn_mfma_f32_16x16x32_bf16(a1, b0, acc10, 0, 0, 0);
    acc11 = __builtin_amdgcn_mfma_f32_16x16x32_bf16(a1, b1, acc11, 0, 0, 0);
  }
}

// ---------------- persistent free-running kernel ----------------
__global__ __launch_bounds__(256, 1) void lstm_async(
    const u16* __restrict__ Xbf, const u16* __restrict__ Wcat,
    const float* __restrict__ bias, unsigned* __restrict__ H0R,
    unsigned* __restrict__ H1R, const float* __restrict__ c0,
    float* __restrict__ out, unsigned* __restrict__ flags)
{
  // 128 KiB swizzled weights + 16 KiB reduction
  __shared__ __align__(16) unsigned char smem[131072 + 16384];
  float* redf = (float*)(smem + 131072);

  const bool is_l1 = (blockIdx.x >= 128);
  const int l  = is_l1 ? 1 : 0;
  const int cb = blockIdx.x & 127;
  const int j0 = cb << 3;                  // 8 hidden units per block
  const int tid = threadIdx.x;
  const int lane = tid & 63;
  const int wid  = tid >> 6;
  const int l15  = lane & 15;
  const int lq   = lane >> 4;
  const int koff = lq << 3;
  const int k0   = wid << 9;               // wave K-slice: 512
  const int xsw  = (l15 & 7) << 4;         // LDS XOR swizzle for B reads
  const int kbyte_base = (k0 + koff) * 2;

  // ---- stage this block's 32 weight rows into LDS (XOR-swizzled) ----
  {
    const int kb = tid * 16;               // byte within a 4096B row
    for (int pr = 0; pr < 32; ++pr) {      // packed rows: [i x8][f x8][g x8][o x8]
      const u16* g = Wcat + ((size_t)l * G4H + (size_t)(pr >> 3) * HID + j0 + (pr & 7)) * KCAT;
      short8 v = *(const short8*)((const char*)g + kb);
      *(short8*)(smem + pr * 4096 + (kb ^ ((pr & 7) << 4))) = v;
    }
  }

  // elementwise mapping (one (m, jj) per thread)
  const int m  = tid >> 3;
  const int jj = tid & 7;
  const int j  = j0 + jj;
  const int mt = m >> 4;
  const int mm = m & 15;
  const int rr = mm & 3;
  const int lbase = (mm >> 2) << 4;
  float b4[4];
  #pragma unroll
  for (int g = 0; g < 4; ++g) b4[g] = bias[l * G4H + g * HID + j];

  float* hT = out + MEM_ELEMS;                      // [2][32][1024]
  float* cT = out + MEM_ELEMS + 2 * (size_t)BH;
  const size_t cidx = (size_t)l * BH + (size_t)m * HID + j;
  float c_reg = 0.f;
  unsigned* HwR = is_l1 ? H1R : H0R;
  unsigned bp = 0;   // l0: known lower bound of l1 progress
  __syncthreads();

  for (int s = 0; s < T_STEPS; ++s) {
    // ---- ring backpressure (l0 wid3 only, slack 12, amortized) ----
    if (!is_l1 && wid == 3 && (unsigned)s >= bp + 12u) {
      const unsigned need = (unsigned)s - 8u;
      const unsigned* p0 = flags + lane * 16;
      const unsigned* p1 = flags + (lane + 64) * 16;
      for (;;) {
        unsigned a = __hip_atomic_load(p0, __ATOMIC_RELAXED, __HIP_MEMORY_SCOPE_AGENT);
        unsigned b = __hip_atomic_load(p1, __ATOMIC_RELAXED, __HIP_MEMORY_SCOPE_AGENT);
        if (__all((int)(a >= need && b >= need))) break;
        __builtin_amdgcn_s_sleep(4);
      }
      bp = need;
    }

    f32x4 acc00 = {0.f, 0.f, 0.f, 0.f};
    f32x4 acc01 = acc00, acc10 = acc00, acc11 = acc00;

    if (!is_l1 && wid < 2) {
      // x-part from bf16 X (no dependency)
      const u16* xs = Xbf + (size_t)s * BH;
      const u16* ab0 = xs + (size_t)l15 * HID + k0 + koff;
      const u16* ab1 = xs + (size_t)(16 + l15) * HID + k0 + koff;
      mfma_batched_pl(smem, ab0, ab1, kbyte_base, xsw, l15, acc00, acc01, acc10, acc11);
    } else {
      // parity-tagged h: l0 wid2,3 -> h0[s]; l1 wid0,1 -> h0[s+1]; l1 wid2,3 -> h1[s]
      const int t = (is_l1 && wid < 2) ? (s + 1) : s;
      const unsigned* hb = ((is_l1 && wid >= 2) ? H1R : H0R) + (size_t)(t & 15) * BH;
      const unsigned tag = (unsigned)(t % 7) + 1u;
      const int col0 = ((wid < 2) ? k0 : (k0 - HID)) + koff;
      const int row0col = l15 * HID + col0;
      const int row1col = (16 + l15) * HID + col0;
      mfma_parity_half(smem, hb, row0col, row1col, tag, 0,
                       kbyte_base, xsw, l15, acc00, acc01, acc10, acc11);
      mfma_parity_half(smem, hb, row0col, row1col, tag, 8,
                       kbyte_base, xsw, l15, acc00, acc01, acc10, acc11);
    }

    *(f32x4*)(redf + ((wid * 2 + 0) * 2 + 0) * 256 + lane * 4) = acc00;
    *(f32x4*)(redf + ((wid * 2 + 0) * 2 + 1) * 256 + lane * 4) = acc01;
    *(f32x4*)(redf + ((wid * 2 + 1) * 2 + 0) * 256 + lane * 4) = acc10;
    *(f32x4*)(redf + ((wid * 2 + 1) * 2 + 1) * 256 + lane * 4) = acc11;
    __syncthreads();   // A: accs staged

    float g4[4];
    #pragma unroll
    for (int gate = 0; gate < 4; ++gate) {
      const int nt = gate >> 1;
      const int nn = ((gate & 1) << 3) + jj;
      const int li = (lbase | nn) * 4 + rr;
      float v = redf[((0 * 2 + mt) * 2 + nt) * 256 + li] +
                redf[((1 * 2 + mt) * 2 + nt) * 256 + li] +
                redf[((2 * 2 + mt) * 2 + nt) * 256 + li] +
                redf[((3 * 2 + mt) * 2 + nt) * 256 + li];
      g4[gate] = v + b4[gate];
    }
    const float c_old = (s == 0) ? c0[cidx] : c_reg;
    const float ig = sigm(g4[0]);
    const float fg = sigm(g4[1]);
    const float gg = tanhf(g4[2]);
    const float og = sigm(g4[3]);
    const float c_new = fg * c_old + ig * gg;
    const float h_new = og * tanhf(c_new);
    c_reg = c_new;
    // publish tagged f32 h@(s+1) into ring (agent store, fire-and-forget)
    {
      const int t1 = s + 1;
      unsigned hv = (__builtin_bit_cast(unsigned, h_new) & ~7u)
                    | ((unsigned)(t1 % 7) + 1u);
      __hip_atomic_store(HwR + (size_t)(t1 & 15) * BH + (size_t)m * HID + j, hv,
                         __ATOMIC_RELAXED, __HIP_MEMORY_SCOPE_AGENT);
    }
    if (is_l1) out[(size_t)s * BH + (size_t)m * HID + j] = h_new;
    if (s == T_STEPS - 1) { hT[cidx] = h_new; cT[cidx] = c_new; }
    __syncthreads();   // B: redf consumed; block-wide stores drained

    // l1 publishes progress (backpressure only; off critical path)
    if (is_l1 && wid == 3 && lane == 0)
      __hip_atomic_store(flags + cb * 16, (unsigned)(s + 1),
                         __ATOMIC_RELAXED, __HIP_MEMORY_SCOPE_AGENT);
  }
}

// ---------------- tier-2: per-step launches (round-1, known-good) ----------------
__global__ void cvt_t2(const float* __restrict__ Wih, const float* __restrict__ Whh,
                       const float* __restrict__ bih, const float* __restrict__ bhh,
                       const float* __restrict__ h0,
                       u16* __restrict__ Wcat, float* __restrict__ bias,
                       u16* __restrict__ h0pp, u16* __restrict__ h1pp) {
  size_t idx = (size_t)blockIdx.x * blockDim.x + threadIdx.x;
  size_t stride = (size_t)gridDim.x * blockDim.x;
  const size_t NW = (size_t)2 * G4H * KCAT;
  for (size_t i = idx; i < NW; i += stride) {
    size_t ln = i >> 11;
    int k = (int)(i & 2047);
    float v = (k < HID) ? Wih[ln * HID + k] : Whh[ln * HID + (k - HID)];
    Wcat[i] = f2bf(v);
  }
  for (size_t i = idx; i < (size_t)2 * G4H; i += stride) bias[i] = bih[i] + bhh[i];
  for (size_t i = idx; i < (size_t)2 * BH; i += stride) {
    unsigned short v = f2bf(h0[i]);
    if (i < (size_t)BH) h0pp[(size_t)BH + i] = v;
    else                h1pp[(size_t)BH + (i - BH)] = v;
  }
}

__global__ __launch_bounds__(256) void lstm_step(
    const float* __restrict__ input, const u16* __restrict__ Wcat,
    const float* __restrict__ bias, u16* __restrict__ h0pp, u16* __restrict__ h1pp,
    const float* __restrict__ c0, float* __restrict__ out, int t)
{
  const bool is_l1 = (blockIdx.x >= 128);
  const int s = is_l1 ? (t - 1) : t;
  if (s < 0 || s >= T_STEPS) return;
  const int l = is_l1 ? 1 : 0;
  const int cb = blockIdx.x & 127;
  const int j0 = cb << 3;
  const int tid = threadIdx.x;
  const int lane = tid & 63;
  const int wid = tid >> 6;
  const int l15 = lane & 15;
  const int lq  = lane >> 4;
  const int koff = lq << 3;
  const int k0 = wid << 9;

  const int row0 = (l15 < 8) ? (j0 + l15) : (HID + j0 + l15 - 8);
  const int row1 = (l15 < 8) ? (2 * HID + j0 + l15) : (3 * HID + j0 + l15 - 8);
  const u16* bp0 = Wcat + ((size_t)l * G4H + row0) * KCAT + k0 + koff;
  const u16* bp1 = Wcat + ((size_t)l * G4H + row1) * KCAT + k0 + koff;

  f32x4 acc00 = {0.f, 0.f, 0.f, 0.f};
  f32x4 acc01 = acc00, acc10 = acc00, acc11 = acc00;

  const bool a_f32 = (!is_l1) && (wid < 2);
  if (a_f32) {
    const float* base = input + (size_t)s * BH + k0 + koff;
    const float* af0 = base + (size_t)l15 * HID;
    const float* af1 = base + (size_t)(16 + l15) * HID;
    #pragma unroll 4
    for (int ks = 0; ks < 16; ++ks) {
      const int kk = ks * 32;
      short8 b0 = *(const short8*)(bp0 + kk);
      short8 b1 = *(const short8*)(bp1 + kk);
      float4 x0 = *(const float4*)(af0 + kk);
      float4 x1 = *(const float4*)(af0 + kk + 4);
      float4 y0 = *(const float4*)(af1 + kk);
      float4 y1 = *(const float4*)(af1 + kk + 4);
      short8 a0, a1;
      a0[0] = (short)f2bf(x0.x); a0[1] = (short)f2bf(x0.y);
      a0[2] = (short)f2bf(x0.z); a0[3] = (short)f2bf(x0.w);
      a0[4] = (short)f2bf(x1.x); a0[5] = (short)f2bf(x1.y);
      a0[6] = (short)f2bf(x1.z); a0[7] = (short)f2bf(x1.w);
      a1[0] = (short)f2bf(y0.x); a1[1] = (short)f2bf(y0.y);
      a1[2] = (short)f2bf(y0.z); a1[3] = (short)f2bf(y0.w);
      a1[4] = (short)f2bf(y1.x); a1[5] = (short)f2bf(y1.y);
      a1[6] = (short)f2bf(y1.z); a1[7] = (short)f2bf(y1.w);
      acc00 = __builtin_amdgcn_mfma_f32_16x16x32_bf16(a0, b0, acc00, 0, 0, 0);
      acc01 = __builtin_amdgcn_mfma_f32_16x16x32_bf16(a0, b1, acc01, 0, 0, 0);
      acc10 = __builtin_amdgcn_mfma_f32_16x16x32_bf16(a1, b0, acc10, 0, 0, 0);
      acc11 = __builtin_amdgcn_mfma_f32_16x16x32_bf16(a1, b1, acc11, 0, 0, 0);
    }
  } else {
    const u16* src; int ksrc;
    if (!is_l1)       { src = h0pp + (size_t)(((s + 1) & 1)) * BH; ksrc = k0 - HID; }
    else if (wid < 2) { src = h0pp + (size_t)((s & 1)) * BH;       ksrc = k0;       }
    else              { src = h1pp + (size_t)(((s + 1) & 1)) * BH; ksrc = k0 - HID; }
    const u16* ab0 = src + (size_t)l15 * HID + ksrc + koff;
    const u16* ab1 = src + (size_t)(16 + l15) * HID + ksrc + koff;
    #pragma unroll 4
    for (int ks = 0; ks < 16; ++ks) {
      const int kk = ks * 32;
      short8 b0 = *(const short8*)(bp0 + kk);
      short8 b1 = *(const short8*)(bp1 + kk);
      short8 a0 = *(const short8*)(ab0 + kk);
      short8 a1 = *(const short8*)(ab1 + kk);
      acc00 = __builtin_amdgcn_mfma_f32_16x16x32_bf16(a0, b0, acc00, 0, 0, 0);
      acc01 = __builtin_amdgcn_mfma_f32_16x16x32_bf16(a0, b1, acc01, 0, 0, 0);
      acc10 = __builtin_amdgcn_mfma_f32_16x16x32_bf16(a1, b0, acc10, 0, 0, 0);
      acc11 = __builtin_amdgcn_mfma_f32_16x16x32_bf16(a1, b1, acc11, 0, 0, 0);
    }
  }

  __shared__ float red[4][2][2][256];
  #pragma unroll
  for (int r = 0; r < 4; ++r) {
    red[wid][0][0][lane * 4 + r] = acc00[r];
    red[wid][0][1][lane * 4 + r] = acc01[r];
    red[wid][1][0][lane * 4 + r] = acc10[r];
    red[wid][1][1][lane * 4 + r] = acc11[r];
  }
  __syncthreads();

  const int m  = tid >> 3;
  const int jj = tid & 7;
  const int j  = j0 + jj;
  const int mt = m >> 4;
  const int mm = m & 15;
  const int rr = mm & 3;
  const int lbase = (mm >> 2) << 4;

  float g4[4];
  #pragma unroll
  for (int gate = 0; gate < 4; ++gate) {
    const int nt = gate >> 1;
    const int nn = ((gate & 1) << 3) + jj;
    const int li = (lbase | nn) * 4 + rr;
    float v = red[0][mt][nt][li] + red[1][mt][nt][li] +
              red[2][mt][nt][li] + red[3][mt][nt][li];
    g4[gate] = v + bias[l * G4H + gate * HID + j];
  }

  float* hT     = out + MEM_ELEMS;
  float* cstate = out + MEM_ELEMS + 2 * (size_t)BH;
  const size_t cidx = (size_t)l * BH + (size_t)m * HID + j;
  const float c_old = (s == 0) ? c0[cidx] : cstate[cidx];
  const float c_new = sigm(g4[1]) * c_old + sigm(g4[0]) * tanhf(g4[2]);
  const float h_new = sigm(g4[3]) * tanhf(c_new);
  cstate[cidx] = c_new;
  u16* ppw = (is_l1 ? h1pp : h0pp) + (size_t)(s & 1) * BH;
  ppw[m * HID + j] = f2bf(h_new);
  if (is_l1) out[(size_t)s * BH + (size_t)m * HID + j] = h_new;
  if (s == T_STEPS - 1) hT[cidx] = h_new;
}

// ---------------- tier-3: fp32 fallback ----------------
__global__ void fb_init(const float* __restrict__ h0, float* __restrict__ h0ppf,
                        float* __restrict__ h1ppf) {
  int i = blockIdx.x * blockDim.x + threadIdx.x;
  if (i < BH) h0ppf[BH + i] = h0[i];
  else if (i < 2 * BH) h1ppf[BH + (i - BH)] = h0[i];
}

__global__ __launch_bounds__(256) void fb_step(
    const float* __restrict__ input, const float* __restrict__ Wih,
    const float* __restrict__ Whh, const float* __restrict__ bih,
    const float* __restrict__ bhh, float* __restrict__ h0ppf, float* __restrict__ h1ppf,
    const float* __restrict__ c0, float* __restrict__ out, int t)
{
  const bool is_l1 = (blockIdx.x >= 128);
  const int s = is_l1 ? (t - 1) : t;
  if (s < 0 || s >= T_STEPS) return;
  const int l = is_l1 ? 1 : 0;
  const int cb = blockIdx.x & 127, j0 = cb << 3, tid = threadIdx.x;
  const float* xsrc = is_l1 ? (h0ppf + (size_t)(s & 1) * BH) : (input + (size_t)s * BH);
  const float* hsrc = (is_l1 ? h1ppf : h0ppf) + (size_t)((s + 1) & 1) * BH;
  const int c = tid & 31, mg = tid >> 5;
  const int gate = c >> 3, jc = c & 7;
  const int row = gate * HID + j0 + jc;
  const float* wi = Wih + ((size_t)l * G4H + row) * HID;
  const float* wh = Whh + ((size_t)l * G4H + row) * HID;
  float a0 = 0, a1 = 0, a2 = 0, a3 = 0;
  const float* x0 = xsrc + (size_t)(mg * 4 + 0) * HID;
  const float* x1 = xsrc + (size_t)(mg * 4 + 1) * HID;
  const float* x2 = xsrc + (size_t)(mg * 4 + 2) * HID;
  const float* x3 = xsrc + (size_t)(mg * 4 + 3) * HID;
  const float* h0p = hsrc + (size_t)(mg * 4 + 0) * HID;
  const float* h1p = hsrc + (size_t)(mg * 4 + 1) * HID;
  const float* h2p = hsrc + (size_t)(mg * 4 + 2) * HID;
  const float* h3p = hsrc + (size_t)(mg * 4 + 3) * HID;
  for (int k = 0; k < HID; ++k) {
    float wa = wi[k], wb = wh[k];
    a0 += x0[k] * wa + h0p[k] * wb;
    a1 += x1[k] * wa + h1p[k] * wb;
    a2 += x2[k] * wa + h2p[k] * wb;
    a3 += x3[k] * wa + h3p[k] * wb;
  }
  __shared__ float gl[32][32];
  const float bsum = bih[l * G4H + row] + bhh[l * G4H + row];
  gl[mg * 4 + 0][c] = a0 + bsum;
  gl[mg * 4 + 1][c] = a1 + bsum;
  gl[mg * 4 + 2][c] = a2 + bsum;
  gl[mg * 4 + 3][c] = a3 + bsum;
  __syncthreads();
  const int m = tid >> 3, jj = tid & 7, j = j0 + jj;
  float g4[4];
  #pragma unroll
  for (int g = 0; g < 4; ++g) g4[g] = gl[m][g * 8 + jj];
  float* hT = out + MEM_ELEMS;
  float* cstate = out + MEM_ELEMS + 2 * (size_t)BH;
  const size_t cidx = (size_t)l * BH + (size_t)m * HID + j;
  const float c_old = (s == 0) ? c0[cidx] : cstate[cidx];
  const float c_new = sigm(g4[1]) * c_old + sigm(g4[0]) * tanhf(g4[2]);
  const float h_new = sigm(g4[3]) * tanhf(c_new);
  cstate[cidx] = c_new;
  float* ppw = (is_l1 ? h1ppf : h0ppf) + (size_t)(s & 1) * BH;
  ppw[m * HID + j] = h_new;
  if (is_l1) out[(size_t)s * BH + (size_t)m * HID + j] = h_new;
  if (s == T_STEPS - 1) hT[cidx] = h_new;
}

extern "C" void kernel_launch(void* const* d_in, const int* in_sizes, int n_in,
                              void* d_out, int out_size, void* d_ws, size_t ws_size,
                              hipStream_t stream) {
  const float* input = (const float*)d_in[0];
  const float* h0    = (const float*)d_in[1];
  const float* c0    = (const float*)d_in[2];
  const float* Wih   = (const float*)d_in[3];
  const float* Whh   = (const float*)d_in[4];
  const float* bih   = (const float*)d_in[5];
  const float* bhh   = (const float*)d_in[6];
  float* out = (float*)d_out;
  char* ws = (char*)d_ws;

  if (ws_size >= WS_PAR) {
    u16*   Wcat = (u16*)(ws + OFF_W);
    float* bias = (float*)(ws + OFF_BIAS);
    unsigned* H0R = (unsigned*)(ws + OFF_H0R);
    unsigned* H1R = (unsigned*)(ws + OFF_H1R);
    unsigned* flags = (unsigned*)(ws + OFF_FLAG);
    u16*   Xbf  = (u16*)(ws + OFF_X);

    int occ = 0;   // all 256 blocks must be co-resident
    (void)hipOccupancyMaxActiveBlocksPerMultiprocessor(&occ, lstm_async, 256, 0);
    if (occ >= 1) {
      // rings + flags must be zeroed BEFORE cvt writes slot 0 (replay safety)
      hipMemsetAsync(ws + OFF_H0R, 0, 2 * SZ_RING + SZ_FLAG, stream);
      cvt_kernel<<<4096, 256, 0, stream>>>(Wih, Whh, bih, bhh, h0, input,
                                           Wcat, bias, H0R, H1R, Xbf);
      lstm_async<<<256, 256, 0, stream>>>(Xbf, Wcat, bias, H0R, H1R, c0, out, flags);
      return;
    }
  }
  if (ws_size >= WS_STEP) {
    u16*   Wcat = (u16*)(ws + OFF_W);
    float* bias = (float*)(ws + T2_BIAS);
    u16*   h0pp = (u16*)(ws + T2_H0);
    u16*   h1pp = (u16*)(ws + T2_H1);
    cvt_t2<<<4096, 256, 0, stream>>>(Wih, Whh, bih, bhh, h0, Wcat, bias, h0pp, h1pp);
    for (int t = 0; t <= T_STEPS; ++t)
      lstm_step<<<256, 256, 0, stream>>>(input, Wcat, bias, h0pp, h1pp, c0, out, t);
  } else {
    float* h0ppf = (float*)ws;
    float* h1ppf = (float*)(ws + (size_t)2 * BH * 4);
    fb_init<<<256, 256, 0, stream>>>(h0, h0ppf, h1ppf);
    for (int t = 0; t <= T_STEPS; ++t)
      fb_step<<<256, 256, 0, stream>>>(input, Wih, Whh, bih, bhh, h0ppf, h1ppf, c0, out, t);
  }
}

// Round 16
// 2988.589 us; speedup vs baseline: 2.1192x; 2.1192x over previous
//
#include <hip/hip_runtime.h>
#include <hip/hip_bf16.h>

// LSTM T=512 B=32 IN=H=1024 L=2. fp32 in/out, bf16 MFMA internally.
// Round 16 = round 14 verbatim (best validated: 2996us, absmax 0.015625).
// Design: persistent free-running blocks; versioned write-once h buffers read
// via plain cached loads; per-producer flag words; epoch aggregation with
// 8x-replicated EP lines; direct per-thread h publish ordered by syncthreads'
// vmcnt drain. r11/r12/r15 established the alternatives all regress.

namespace {
constexpr int T_STEPS = 512;
constexpr int BATCH   = 32;
constexpr int HID     = 1024;
constexpr int G4H     = 4096;
constexpr int KCAT    = 2048;
constexpr int BH      = BATCH * HID;                 // 32768
constexpr size_t MEM_ELEMS = (size_t)T_STEPS * BH;   // 16,777,216

// workspace layout (bytes)
constexpr size_t OFF_W    = 0;
constexpr size_t SZ_W     = (size_t)2 * G4H * KCAT * 2;     // 33.55 MB bf16 W_cat
constexpr size_t OFF_BIAS = OFF_W + SZ_W;                   // f32 [2][4096]
constexpr size_t OFF_H0V  = OFF_BIAS + 32768;               // bf16 [513][32][1024]
constexpr size_t SZ_HV    = (size_t)(T_STEPS + 1) * BH * 2; // 33.62 MB
constexpr size_t OFF_H1V  = OFF_H0V + SZ_HV;
constexpr size_t OFF_FLAG = OFF_H1V + SZ_HV;                // u32[2][128]@16B + EP replicas
constexpr size_t SZ_FLAG  = 8192;
constexpr size_t OFF_X    = OFF_FLAG + SZ_FLAG;             // bf16 X [512][32][1024]
constexpr size_t WS_ASYNC = OFF_X + MEM_ELEMS * 2;          // ~135 MB
constexpr size_t WS_STEP  = OFF_H0V + (size_t)4 * BH * 2;   // tier-2: pp buffers only

// EP replica word offsets inside flags[]: EP0 copies at 1024+k*16, EP1 at 1536+k*16
constexpr int EP0_W = 1024;
constexpr int EP1_W = 1536;
}

typedef __attribute__((ext_vector_type(8))) short short8;
typedef __attribute__((ext_vector_type(4))) float f32x4;
typedef unsigned short u16;
typedef unsigned long long u64;

__device__ inline unsigned short f2bf(float x) {
  unsigned u = __builtin_bit_cast(unsigned, x);
  u += 0x7fffu + ((u >> 16) & 1u);          // RNE
  return (unsigned short)(u >> 16);
}
__device__ inline float sigm(float x) { return 1.0f / (1.0f + __expf(-x)); }

// ---------------- conversion: W_cat bf16, bias sum, initial h, X bf16 ----------------
__global__ void cvt_kernel(const float* __restrict__ Wih, const float* __restrict__ Whh,
                           const float* __restrict__ bih, const float* __restrict__ bhh,
                           const float* __restrict__ h0, const float* __restrict__ input,
                           u16* __restrict__ Wcat, float* __restrict__ bias,
                           u16* __restrict__ H0i, u16* __restrict__ H1i,
                           u16* __restrict__ Xbf) {
  size_t idx = (size_t)blockIdx.x * blockDim.x + threadIdx.x;
  size_t stride = (size_t)gridDim.x * blockDim.x;
  const size_t NW = (size_t)2 * G4H * KCAT;
  for (size_t i = idx; i < NW; i += stride) {
    size_t ln = i >> 11;                 // l*4096 + n
    int k = (int)(i & 2047);
    float v = (k < HID) ? Wih[ln * HID + k] : Whh[ln * HID + (k - HID)];
    Wcat[i] = f2bf(v);
  }
  for (size_t i = idx; i < (size_t)2 * G4H; i += stride) bias[i] = bih[i] + bhh[i];
  for (size_t i = idx; i < (size_t)2 * BH; i += stride) {
    unsigned short v = f2bf(h0[i]);
    if (i < (size_t)BH) H0i[i] = v;       // slot 0 = h at time 0
    else                H1i[i - BH] = v;
  }
  if (Xbf) {
    for (size_t i = idx; i < MEM_ELEMS; i += stride) Xbf[i] = f2bf(input[i]);
  }
}

// batched plain-cached loads for A fragments, then MFMA from registers + LDS B
__device__ __attribute__((always_inline)) void mfma_batched_pl(
    const unsigned char* smem, const u16* ab0, const u16* ab1,
    int kbyte_base, int xsw, int l15,
    f32x4& acc00, f32x4& acc01, f32x4& acc10, f32x4& acc11) {
  u64 ra0[16], ra1[16], rb0[16], rb1[16];
  #pragma unroll
  for (int ks = 0; ks < 16; ++ks) {
    const u64* q0 = (const u64*)(ab0 + ks * 32);
    const u64* q1 = (const u64*)(ab1 + ks * 32);
    ra0[ks] = q0[0]; ra1[ks] = q0[1];
    rb0[ks] = q1[0]; rb1[ks] = q1[1];
  }
  #pragma unroll
  for (int ks = 0; ks < 16; ++ks) {
    const int kb2 = kbyte_base + ks * 64;
    short8 b0 = *(const short8*)(smem + l15 * 4096 + (kb2 ^ xsw));
    short8 b1 = *(const short8*)(smem + (16 + l15) * 4096 + (kb2 ^ xsw));
    union { u64 u[2]; short8 s; } ua, ub;
    ua.u[0] = ra0[ks]; ua.u[1] = ra1[ks];
    ub.u[0] = rb0[ks]; ub.u[1] = rb1[ks];
    acc00 = __builtin_amdgcn_mfma_f32_16x16x32_bf16(ua.s, b0, acc00, 0, 0, 0);
    acc01 = __builtin_amdgcn_mfma_f32_16x16x32_bf16(ua.s, b1, acc01, 0, 0, 0);
    acc10 = __builtin_amdgcn_mfma_f32_16x16x32_bf16(ub.s, b0, acc10, 0, 0, 0);
    acc11 = __builtin_amdgcn_mfma_f32_16x16x32_bf16(ub.s, b1, acc11, 0, 0, 0);
  }
}

// ---------------- persistent free-running kernel ----------------
__global__ __launch_bounds__(256, 1) void lstm_async(
    const u16* __restrict__ Xbf, const u16* __restrict__ Wcat,
    const float* __restrict__ bias, u16* __restrict__ H0v, u16* __restrict__ H1v,
    const float* __restrict__ c0, float* __restrict__ out, unsigned* __restrict__ flags)
{
  // 128 KiB swizzled weights + 16 KiB reduction + 512 B spare + 64 B mirrors
  __shared__ __align__(16) unsigned char smem[131072 + 16384 + 512 + 64];
  float* redf   = (float*)(smem + 131072);
  volatile unsigned* epl = (volatile unsigned*)(smem + 131072 + 16384 + 512);

  const bool is_l1 = (blockIdx.x >= 128);
  const int l  = is_l1 ? 1 : 0;
  const int cb = blockIdx.x & 127;
  const bool is_agg = (cb == 0);
  const int j0 = cb << 3;                  // 8 hidden units per block
  const int tid = threadIdx.x;
  const int lane = tid & 63;
  const int wid  = tid >> 6;
  const int l15  = lane & 15;
  const int lq   = lane >> 4;
  const int koff = lq << 3;
  const int k0   = wid << 9;               // wave K-slice: 512
  const int xsw  = (l15 & 7) << 4;         // LDS XOR swizzle for B reads
  const int kbyte_base = (k0 + koff) * 2;
  const int epc = (cb & 7) * 16;           // this block's EP replica word offset

  // ---- stage this block's 32 weight rows into LDS (XOR-swizzled) ----
  {
    const int kb = tid * 16;               // byte within a 4096B row
    for (int pr = 0; pr < 32; ++pr) {      // packed rows: [i x8][f x8][g x8][o x8]
      const u16* g = Wcat + ((size_t)l * G4H + (size_t)(pr >> 3) * HID + j0 + (pr & 7)) * KCAT;
      short8 v = *(const short8*)((const char*)g + kb);
      *(short8*)(smem + pr * 4096 + (kb ^ ((pr & 7) << 4))) = v;
    }
  }
  if (tid < 2) epl[tid] = 0;

  // elementwise mapping (one (m, jj) per thread)
  const int m  = tid >> 3;
  const int jj = tid & 7;
  const int j  = j0 + jj;
  const int mt = m >> 4;
  const int mm = m & 15;
  const int rr = mm & 3;
  const int lbase = (mm >> 2) << 4;
  float b4[4];
  #pragma unroll
  for (int g = 0; g < 4; ++g) b4[g] = bias[l * G4H + g * HID + j];

  float* hT = out + MEM_ELEMS;                      // [2][32][1024]
  float* cT = out + MEM_ELEMS + 2 * (size_t)BH;
  const size_t cidx = (size_t)l * BH + (size_t)m * HID + j;
  float c_reg = 0.f;
  u16* Hw = is_l1 ? H1v : H0v;
  unsigned* myflag = flags + (size_t)(l * 128 + cb) * 4;
  __syncthreads();

  for (int s = 0; s < T_STEPS; ++s) {
    // ---------- dependency wait (epoch-aggregated, replicated EP lines) ----------
    if (!is_l1) {
      if (wid == 2) {
        const unsigned need = (unsigned)s;
        if (need) {
          if (is_agg) {
            const unsigned* p0 = flags + lane * 4;
            const unsigned* p1 = flags + (lane + 64) * 4;
            for (;;) {
              unsigned a = __hip_atomic_load(p0, __ATOMIC_RELAXED, __HIP_MEMORY_SCOPE_AGENT);
              unsigned b = __hip_atomic_load(p1, __ATOMIC_RELAXED, __HIP_MEMORY_SCOPE_AGENT);
              if (__all((int)(a >= need && b >= need))) break;
              __builtin_amdgcn_s_sleep(2);
            }
            if (lane < 8)
              __hip_atomic_store(flags + EP0_W + lane * 16, need,
                                 __ATOMIC_RELAXED, __HIP_MEMORY_SCOPE_AGENT);
          } else {
            while (__hip_atomic_load(flags + EP0_W + epc, __ATOMIC_RELAXED,
                                     __HIP_MEMORY_SCOPE_AGENT) < need)
              __builtin_amdgcn_s_sleep(2);
          }
          if (lane == 0) epl[0] = need;
        }
      } else if (wid == 3) {
        const unsigned need = (unsigned)s;
        while (epl[0] < need) __builtin_amdgcn_s_sleep(1);
      }
      // wid 0,1 (x-part): no wait
    } else {
      if (wid == 2) {
        const unsigned need = (unsigned)s;
        if (need) {
          if (is_agg) {
            const unsigned* p0 = flags + 512 + lane * 4;
            const unsigned* p1 = flags + 512 + (lane + 64) * 4;
            for (;;) {
              unsigned a = __hip_atomic_load(p0, __ATOMIC_RELAXED, __HIP_MEMORY_SCOPE_AGENT);
              unsigned b = __hip_atomic_load(p1, __ATOMIC_RELAXED, __HIP_MEMORY_SCOPE_AGENT);
              if (__all((int)(a >= need && b >= need))) break;
              __builtin_amdgcn_s_sleep(2);
            }
            if (lane < 8)
              __hip_atomic_store(flags + EP1_W + lane * 16, need,
                                 __ATOMIC_RELAXED, __HIP_MEMORY_SCOPE_AGENT);
          } else {
            while (__hip_atomic_load(flags + EP1_W + epc, __ATOMIC_RELAXED,
                                     __HIP_MEMORY_SCOPE_AGENT) < need)
              __builtin_amdgcn_s_sleep(2);
          }
          if (lane == 0) epl[1] = need;
        }
      } else if (wid == 3) {
        const unsigned need0 = (unsigned)(s + 1);
        while (__hip_atomic_load(flags + EP0_W + epc, __ATOMIC_RELAXED,
                                 __HIP_MEMORY_SCOPE_AGENT) < need0)
          __builtin_amdgcn_s_sleep(2);
        if (lane == 0) epl[0] = need0;
        const unsigned need = (unsigned)s;
        while (epl[1] < need) __builtin_amdgcn_s_sleep(1);
      } else {  // wid 0,1 (x-part = h0[s+1])
        const unsigned need0 = (unsigned)(s + 1);
        while (epl[0] < need0) __builtin_amdgcn_s_sleep(1);
      }
    }
    asm volatile("" ::: "memory");   // keep h loads below the wait

    // ---------- source & MFMA (all plain cached loads) ----------
    const u16* src; int ksrc;
    if (!is_l1) {
      if (wid < 2) { src = Xbf + (size_t)s * BH;       ksrc = k0; }
      else         { src = H0v + (size_t)s * BH;       ksrc = k0 - HID; }
    } else {
      if (wid < 2) { src = H0v + (size_t)(s + 1) * BH; ksrc = k0; }
      else         { src = H1v + (size_t)s * BH;       ksrc = k0 - HID; }
    }
    const u16* ab0 = src + (size_t)l15 * HID + ksrc + koff;
    const u16* ab1 = src + (size_t)(16 + l15) * HID + ksrc + koff;
    f32x4 acc00 = {0.f, 0.f, 0.f, 0.f};
    f32x4 acc01 = acc00, acc10 = acc00, acc11 = acc00;
    mfma_batched_pl(smem, ab0, ab1, kbyte_base, xsw, l15, acc00, acc01, acc10, acc11);

    *(f32x4*)(redf + ((wid * 2 + 0) * 2 + 0) * 256 + lane * 4) = acc00;
    *(f32x4*)(redf + ((wid * 2 + 0) * 2 + 1) * 256 + lane * 4) = acc01;
    *(f32x4*)(redf + ((wid * 2 + 1) * 2 + 0) * 256 + lane * 4) = acc10;
    *(f32x4*)(redf + ((wid * 2 + 1) * 2 + 1) * 256 + lane * 4) = acc11;
    __syncthreads();   // A: accs staged

    float g4[4];
    #pragma unroll
    for (int gate = 0; gate < 4; ++gate) {
      const int nt = gate >> 1;
      const int nn = ((gate & 1) << 3) + jj;
      const int li = (lbase | nn) * 4 + rr;
      float v = redf[((0 * 2 + mt) * 2 + nt) * 256 + li] +
                redf[((1 * 2 + mt) * 2 + nt) * 256 + li] +
                redf[((2 * 2 + mt) * 2 + nt) * 256 + li] +
                redf[((3 * 2 + mt) * 2 + nt) * 256 + li];
      g4[gate] = v + b4[gate];
    }
    const float c_old = (s == 0) ? c0[cidx] : c_reg;
    const float ig = sigm(g4[0]);
    const float fg = sigm(g4[1]);
    const float gg = tanhf(g4[2]);
    const float og = sigm(g4[3]);
    const float c_new = fg * c_old + ig * gg;
    const float h_new = og * tanhf(c_new);
    c_reg = c_new;
    // direct per-thread agent-scope publish (write-through, issued early;
    // drained by sync B's vmcnt(0) before the flag fires)
    __hip_atomic_store(Hw + (size_t)(s + 1) * BH + (size_t)m * HID + j,
                       (u16)f2bf(h_new), __ATOMIC_RELAXED, __HIP_MEMORY_SCOPE_AGENT);
    if (is_l1) out[(size_t)s * BH + (size_t)m * HID + j] = h_new;
    if (s == T_STEPS - 1) { hT[cidx] = h_new; cT[cidx] = c_new; }
    __syncthreads();   // B: all h stores drained (vmcnt 0 per-wave), redf free

    if (wid == 3 && lane == 0)
      __hip_atomic_store(myflag, (unsigned)(s + 1),
                         __ATOMIC_RELAXED, __HIP_MEMORY_SCOPE_AGENT);
  }

  // ---------- terminal epoch: l1's last step needs EP0 >= 512 ----------
  if (!is_l1 && is_agg && wid == 2) {
    const unsigned need = (unsigned)T_STEPS;
    const unsigned* p0 = flags + lane * 4;
    const unsigned* p1 = flags + (lane + 64) * 4;
    for (;;) {
      unsigned a = __hip_atomic_load(p0, __ATOMIC_RELAXED, __HIP_MEMORY_SCOPE_AGENT);
      unsigned b = __hip_atomic_load(p1, __ATOMIC_RELAXED, __HIP_MEMORY_SCOPE_AGENT);
      if (__all((int)(a >= need && b >= need))) break;
      __builtin_amdgcn_s_sleep(2);
    }
    if (lane < 8)
      __hip_atomic_store(flags + EP0_W + lane * 16, need,
                         __ATOMIC_RELAXED, __HIP_MEMORY_SCOPE_AGENT);
  }
}

// ---------------- tier-2: per-step launches (round-1, known-good) ----------------
__global__ __launch_bounds__(256) void lstm_step(
    const float* __restrict__ input, const u16* __restrict__ Wcat,
    const float* __restrict__ bias, u16* __restrict__ h0pp, u16* __restrict__ h1pp,
    const float* __restrict__ c0, float* __restrict__ out, int t)
{
  const bool is_l1 = (blockIdx.x >= 128);
  const int s = is_l1 ? (t - 1) : t;
  if (s < 0 || s >= T_STEPS) return;
  const int l = is_l1 ? 1 : 0;
  const int cb = blockIdx.x & 127;
  const int j0 = cb << 3;
  const int tid = threadIdx.x;
  const int lane = tid & 63;
  const int wid = tid >> 6;
  const int l15 = lane & 15;
  const int lq  = lane >> 4;
  const int koff = lq << 3;
  const int k0 = wid << 9;

  const int row0 = (l15 < 8) ? (j0 + l15) : (HID + j0 + l15 - 8);
  const int row1 = (l15 < 8) ? (2 * HID + j0 + l15) : (3 * HID + j0 + l15 - 8);
  const u16* bp0 = Wcat + ((size_t)l * G4H + row0) * KCAT + k0 + koff;
  const u16* bp1 = Wcat + ((size_t)l * G4H + row1) * KCAT + k0 + koff;

  f32x4 acc00 = {0.f, 0.f, 0.f, 0.f};
  f32x4 acc01 = acc00, acc10 = acc00, acc11 = acc00;

  const bool a_f32 = (!is_l1) && (wid < 2);
  if (a_f32) {
    const float* base = input + (size_t)s * BH + k0 + koff;
    const float* af0 = base + (size_t)l15 * HID;
    const float* af1 = base + (size_t)(16 + l15) * HID;
    #pragma unroll 4
    for (int ks = 0; ks < 16; ++ks) {
      const int kk = ks * 32;
      short8 b0 = *(const short8*)(bp0 + kk);
      short8 b1 = *(const short8*)(bp1 + kk);
      float4 x0 = *(const float4*)(af0 + kk);
      float4 x1 = *(const float4*)(af0 + kk + 4);
      float4 y0 = *(const float4*)(af1 + kk);
      float4 y1 = *(const float4*)(af1 + kk + 4);
      short8 a0, a1;
      a0[0] = (short)f2bf(x0.x); a0[1] = (short)f2bf(x0.y);
      a0[2] = (short)f2bf(x0.z); a0[3] = (short)f2bf(x0.w);
      a0[4] = (short)f2bf(x1.x); a0[5] = (short)f2bf(x1.y);
      a0[6] = (short)f2bf(x1.z); a0[7] = (short)f2bf(x1.w);
      a1[0] = (short)f2bf(y0.x); a1[1] = (short)f2bf(y0.y);
      a1[2] = (short)f2bf(y0.z); a1[3] = (short)f2bf(y0.w);
      a1[4] = (short)f2bf(y1.x); a1[5] = (short)f2bf(y1.y);
      a1[6] = (short)f2bf(y1.z); a1[7] = (short)f2bf(y1.w);
      acc00 = __builtin_amdgcn_mfma_f32_16x16x32_bf16(a0, b0, acc00, 0, 0, 0);
      acc01 = __builtin_amdgcn_mfma_f32_16x16x32_bf16(a0, b1, acc01, 0, 0, 0);
      acc10 = __builtin_amdgcn_mfma_f32_16x16x32_bf16(a1, b0, acc10, 0, 0, 0);
      acc11 = __builtin_amdgcn_mfma_f32_16x16x32_bf16(a1, b1, acc11, 0, 0, 0);
    }
  } else {
    const u16* src; int ksrc;
    if (!is_l1)       { src = h0pp + (size_t)(((s + 1) & 1)) * BH; ksrc = k0 - HID; }
    else if (wid < 2) { src = h0pp + (size_t)((s & 1)) * BH;       ksrc = k0;       }
    else              { src = h1pp + (size_t)(((s + 1) & 1)) * BH; ksrc = k0 - HID; }
    const u16* ab0 = src + (size_t)l15 * HID + ksrc + koff;
    const u16* ab1 = src + (size_t)(16 + l15) * HID + ksrc + koff;
    #pragma unroll 4
    for (int ks = 0; ks < 16; ++ks) {
      const int kk = ks * 32;
      short8 b0 = *(const short8*)(bp0 + kk);
      short8 b1 = *(const short8*)(bp1 + kk);
      short8 a0 = *(const short8*)(ab0 + kk);
      short8 a1 = *(const short8*)(ab1 + kk);
      acc00 = __builtin_amdgcn_mfma_f32_16x16x32_bf16(a0, b0, acc00, 0, 0, 0);
      acc01 = __builtin_amdgcn_mfma_f32_16x16x32_bf16(a0, b1, acc01, 0, 0, 0);
      acc10 = __builtin_amdgcn_mfma_f32_16x16x32_bf16(a1, b0, acc10, 0, 0, 0);
      acc11 = __builtin_amdgcn_mfma_f32_16x16x32_bf16(a1, b1, acc11, 0, 0, 0);
    }
  }

  __shared__ float red[4][2][2][256];
  #pragma unroll
  for (int r = 0; r < 4; ++r) {
    red[wid][0][0][lane * 4 + r] = acc00[r];
    red[wid][0][1][lane * 4 + r] = acc01[r];
    red[wid][1][0][lane * 4 + r] = acc10[r];
    red[wid][1][1][lane * 4 + r] = acc11[r];
  }
  __syncthreads();

  const int m  = tid >> 3;
  const int jj = tid & 7;
  const int j  = j0 + jj;
  const int mt = m >> 4;
  const int mm = m & 15;
  const int rr = mm & 3;
  const int lbase = (mm >> 2) << 4;

  float g4[4];
  #pragma unroll
  for (int gate = 0; gate < 4; ++gate) {
    const int nt = gate >> 1;
    const int nn = ((gate & 1) << 3) + jj;
    const int li = (lbase | nn) * 4 + rr;
    float v = red[0][mt][nt][li] + red[1][mt][nt][li] +
              red[2][mt][nt][li] + red[3][mt][nt][li];
    g4[gate] = v + bias[l * G4H + gate * HID + j];
  }

  float* hT     = out + MEM_ELEMS;
  float* cstate = out + MEM_ELEMS + 2 * (size_t)BH;
  const size_t cidx = (size_t)l * BH + (size_t)m * HID + j;
  const float c_old = (s == 0) ? c0[cidx] : cstate[cidx];
  const float ig = sigm(g4[0]);
  const float fg = sigm(g4[1]);
  const float gg = tanhf(g4[2]);
  const float og = sigm(g4[3]);
  const float c_new = fg * c_old + ig * gg;
  const float h_new = og * tanhf(c_new);
  cstate[cidx] = c_new;
  u16* ppw = (is_l1 ? h1pp : h0pp) + (size_t)(s & 1) * BH;
  ppw[m * HID + j] = f2bf(h_new);
  if (is_l1) out[(size_t)s * BH + (size_t)m * HID + j] = h_new;
  if (s == T_STEPS - 1) hT[cidx] = h_new;
}

// ---------------- tier-3: fp32 fallback ----------------
__global__ void fb_init(const float* __restrict__ h0, float* __restrict__ h0ppf,
                        float* __restrict__ h1ppf) {
  int i = blockIdx.x * blockDim.x + threadIdx.x;
  if (i < BH) h0ppf[BH + i] = h0[i];
  else if (i < 2 * BH) h1ppf[BH + (i - BH)] = h0[i];
}

__global__ __launch_bounds__(256) void fb_step(
    const float* __restrict__ input, const float* __restrict__ Wih,
    const float* __restrict__ Whh, const float* __restrict__ bih,
    const float* __restrict__ bhh, float* __restrict__ h0ppf, float* __restrict__ h1ppf,
    const float* __restrict__ c0, float* __restrict__ out, int t)
{
  const bool is_l1 = (blockIdx.x >= 128);
  const int s = is_l1 ? (t - 1) : t;
  if (s < 0 || s >= T_STEPS) return;
  const int l = is_l1 ? 1 : 0;
  const int cb = blockIdx.x & 127, j0 = cb << 3, tid = threadIdx.x;
  const float* xsrc = is_l1 ? (h0ppf + (size_t)(s & 1) * BH) : (input + (size_t)s * BH);
  const float* hsrc = (is_l1 ? h1ppf : h0ppf) + (size_t)((s + 1) & 1) * BH;
  const int c = tid & 31, mg = tid >> 5;
  const int gate = c >> 3, jc = c & 7;
  const int row = gate * HID + j0 + jc;
  const float* wi = Wih + ((size_t)l * G4H + row) * HID;
  const float* wh = Whh + ((size_t)l * G4H + row) * HID;
  float a0 = 0, a1 = 0, a2 = 0, a3 = 0;
  const float* x0 = xsrc + (size_t)(mg * 4 + 0) * HID;
  const float* x1 = xsrc + (size_t)(mg * 4 + 1) * HID;
  const float* x2 = xsrc + (size_t)(mg * 4 + 2) * HID;
  const float* x3 = xsrc + (size_t)(mg * 4 + 3) * HID;
  const float* h0p = hsrc + (size_t)(mg * 4 + 0) * HID;
  const float* h1p = hsrc + (size_t)(mg * 4 + 1) * HID;
  const float* h2p = hsrc + (size_t)(mg * 4 + 2) * HID;
  const float* h3p = hsrc + (size_t)(mg * 4 + 3) * HID;
  for (int k = 0; k < HID; ++k) {
    float wa = wi[k], wb = wh[k];
    a0 += x0[k] * wa + h0p[k] * wb;
    a1 += x1[k] * wa + h1p[k] * wb;
    a2 += x2[k] * wa + h2p[k] * wb;
    a3 += x3[k] * wa + h3p[k] * wb;
  }
  __shared__ float gl[32][32];
  const float bsum = bih[l * G4H + row] + bhh[l * G4H + row];
  gl[mg * 4 + 0][c] = a0 + bsum;
  gl[mg * 4 + 1][c] = a1 + bsum;
  gl[mg * 4 + 2][c] = a2 + bsum;
  gl[mg * 4 + 3][c] = a3 + bsum;
  __syncthreads();
  const int m = tid >> 3, jj = tid & 7, j = j0 + jj;
  float g4[4];
  #pragma unroll
  for (int g = 0; g < 4; ++g) g4[g] = gl[m][g * 8 + jj];
  float* hT = out + MEM_ELEMS;
  float* cstate = out + MEM_ELEMS + 2 * (size_t)BH;
  const size_t cidx = (size_t)l * BH + (size_t)m * HID + j;
  const float c_old = (s == 0) ? c0[cidx] : cstate[cidx];
  const float ig = sigm(g4[0]);
  const float fg = sigm(g4[1]);
  const float gg = tanhf(g4[2]);
  const float og = sigm(g4[3]);
  const float c_new = fg * c_old + ig * gg;
  const float h_new = og * tanhf(c_new);
  cstate[cidx] = c_new;
  float* ppw = (is_l1 ? h1ppf : h0ppf) + (size_t)(s & 1) * BH;
  ppw[m * HID + j] = h_new;
  if (is_l1) out[(size_t)s * BH + (size_t)m * HID + j] = h_new;
  if (s == T_STEPS - 1) hT[cidx] = h_new;
}

extern "C" void kernel_launch(void* const* d_in, const int* in_sizes, int n_in,
                              void* d_out, int out_size, void* d_ws, size_t ws_size,
                              hipStream_t stream) {
  const float* input = (const float*)d_in[0];
  const float* h0    = (const float*)d_in[1];
  const float* c0    = (const float*)d_in[2];
  const float* Wih   = (const float*)d_in[3];
  const float* Whh   = (const float*)d_in[4];
  const float* bih   = (const float*)d_in[5];
  const float* bhh   = (const float*)d_in[6];
  float* out = (float*)d_out;
  char* ws = (char*)d_ws;

  if (ws_size >= WS_ASYNC) {
    u16*   Wcat = (u16*)(ws + OFF_W);
    float* bias = (float*)(ws + OFF_BIAS);
    u16*   H0v  = (u16*)(ws + OFF_H0V);
    u16*   H1v  = (u16*)(ws + OFF_H1V);
    unsigned* flags = (unsigned*)(ws + OFF_FLAG);
    u16*   Xbf  = (u16*)(ws + OFF_X);

    int occ = 0;   // all 256 blocks must be co-resident for free-running flags
    (void)hipOccupancyMaxActiveBlocksPerMultiprocessor(&occ, lstm_async, 256, 0);
    if (occ >= 1) {
      cvt_kernel<<<4096, 256, 0, stream>>>(Wih, Whh, bih, bhh, h0, input,
                                           Wcat, bias, H0v, H1v, Xbf);
      hipMemsetAsync(ws + OFF_FLAG, 0, SZ_FLAG, stream);
      lstm_async<<<256, 256, 0, stream>>>(Xbf, Wcat, bias, H0v, H1v, c0, out, flags);
      return;
    }
  }
  if (ws_size >= WS_STEP) {
    u16*   Wcat = (u16*)(ws + OFF_W);
    float* bias = (float*)(ws + OFF_BIAS);
    u16*   h0pp = (u16*)(ws + OFF_H0V);
    u16*   h1pp = (u16*)(ws + OFF_H0V + (size_t)2 * BH * 2);
    cvt_kernel<<<4096, 256, 0, stream>>>(Wih, Whh, bih, bhh, h0, input,
                                         Wcat, bias, h0pp + BH, h1pp + BH, nullptr);
    for (int t = 0; t <= T_STEPS; ++t)
      lstm_step<<<256, 256, 0, stream>>>(input, Wcat, bias, h0pp, h1pp, c0, out, t);
  } else {
    float* h0ppf = (float*)ws;
    float* h1ppf = (float*)(ws + (size_t)2 * BH * 4);
    fb_init<<<256, 256, 0, stream>>>(h0, h0ppf, h1ppf);
    for (int t = 0; t <= T_STEPS; ++t)
      fb_step<<<256, 256, 0, stream>>>(input, Wih, Whh, bih, bhh, h0ppf, h1ppf, c0, out, t);
  }
}